// Round 4
// baseline (61.719 us; speedup 1.0000x reference)
//
#include <hip/hip_runtime.h>
#include <hip/hip_bf16.h>

// Capsule routing-by-agreement: X [B, N=64, D=64] fp32 -> v [B, 64] fp32.
// One WAVE per 8-element chunk. Next element's 16KB tile is DMA-prefetched
// into a per-wave private LDS buffer via global_load_lds (no VGPR cost),
// while the current element is computed from registers. Zero barriers.
//   lane l (h=l>>4, g=l&15) holds X[4i+h][4g..4g+3], i=0..15  (16 x float4).

#define ELEMS 8
#define WPB   4   // waves per block

__device__ __forceinline__ void dma_tile(const float* __restrict__ gbase,
                                         float* lbuf, int l) {
    // 16 instrs x (64 lanes x 16B) = 16KB. LDS dest = uniform base + lane*16.
    #pragma unroll
    for (int i = 0; i < 16; ++i) {
        __builtin_amdgcn_global_load_lds(
            (const __attribute__((address_space(1))) void*)(gbase + i * 256 + 4 * l),
            (__attribute__((address_space(3))) void*)(lbuf + i * 256),
            16, 0, 0);
    }
}

__global__ __launch_bounds__(256, 2)
void routing_kernel(const float* __restrict__ X, float* __restrict__ out, int B) {
    __shared__ float lds[WPB][4096];           // 64 KB/block, wave-private slices
    const int wv = threadIdx.x >> 6;
    const int l  = threadIdx.x & 63;
    const int g  = l & 15;
    float* buf = lds[wv];

    const long base = ((long)blockIdx.x * WPB + wv) * ELEMS;
    if (base >= B) return;

    dma_tile(X + base * 4096, buf, l);         // prologue: element `base`

    #pragma unroll 1
    for (int e = 0; e < ELEMS; ++e) {
        const long elem = base + e;
        if (elem >= B) break;

        // DMA for this element complete -> LDS valid
        asm volatile("s_waitcnt vmcnt(0)" ::: "memory");

        float4 data[16];
        #pragma unroll
        for (int i = 0; i < 16; ++i)
            data[i] = *reinterpret_cast<const float4*>(buf + i * 256 + 4 * l);

        // reads drained -> safe to overwrite buf with next element's DMA
        asm volatile("s_waitcnt lgkmcnt(0)" ::: "memory");
        if (e + 1 < ELEMS && elem + 1 < B)
            dma_tile(X + (elem + 1) * 4096, buf, l);

        // ---------------- routing compute (register-resident) ----------------
        float blog[16];
        #pragma unroll
        for (int i = 0; i < 16; ++i) blog[i] = 0.0f;
        float4 v4 = make_float4(0.f, 0.f, 0.f, 0.f);

        #pragma unroll
        for (int it = 0; it < 3; ++it) {
            float4 s4;
            if (it == 0) {
                // uniform c = 1/64 -> s = mean over rows
                s4 = make_float4(0.f, 0.f, 0.f, 0.f);
                #pragma unroll
                for (int i = 0; i < 16; ++i) {
                    s4.x += data[i].x; s4.y += data[i].y;
                    s4.z += data[i].z; s4.w += data[i].w;
                }
                s4.x *= 0.015625f; s4.y *= 0.015625f;
                s4.z *= 0.015625f; s4.w *= 0.015625f;
                #pragma unroll
                for (int off = 16; off <= 32; off <<= 1) {
                    s4.x += __shfl_xor(s4.x, off);
                    s4.y += __shfl_xor(s4.y, off);
                    s4.z += __shfl_xor(s4.z, off);
                    s4.w += __shfl_xor(s4.w, off);
                }
            } else {
                // softmax fused with s-accumulate (no c[] array)
                float m = blog[0];
                #pragma unroll
                for (int i = 1; i < 16; ++i) m = fmaxf(m, blog[i]);
                m = fmaxf(m, __shfl_xor(m, 16));
                m = fmaxf(m, __shfl_xor(m, 32));
                float sum = 0.0f;
                s4 = make_float4(0.f, 0.f, 0.f, 0.f);
                #pragma unroll
                for (int i = 0; i < 16; ++i) {
                    const float ei = __expf(blog[i] - m);
                    sum += ei;
                    s4.x = fmaf(ei, data[i].x, s4.x);
                    s4.y = fmaf(ei, data[i].y, s4.y);
                    s4.z = fmaf(ei, data[i].z, s4.z);
                    s4.w = fmaf(ei, data[i].w, s4.w);
                }
                sum += __shfl_xor(sum, 16);
                sum += __shfl_xor(sum, 32);
                #pragma unroll
                for (int off = 16; off <= 32; off <<= 1) {
                    s4.x += __shfl_xor(s4.x, off);
                    s4.y += __shfl_xor(s4.y, off);
                    s4.z += __shfl_xor(s4.z, off);
                    s4.w += __shfl_xor(s4.w, off);
                }
                const float r = 1.0f / sum;
                s4.x *= r; s4.y *= r; s4.z *= r; s4.w *= r;
            }

            // squash
            float n2 = s4.x * s4.x + s4.y * s4.y + s4.z * s4.z + s4.w * s4.w;
            #pragma unroll
            for (int off = 1; off <= 8; off <<= 1) n2 += __shfl_xor(n2, off);
            const float norm = sqrtf(n2);
            const float scale = n2 / (1.0f + n2) / (norm + 1e-8f);
            v4.x = scale * s4.x; v4.y = scale * s4.y;
            v4.z = scale * s4.z; v4.w = scale * s4.w;

            if (it < 2) {
                // agreement: b[4i+h] += X[row] . v   (v lane-local: same cols)
                #pragma unroll
                for (int i = 0; i < 16; ++i) {
                    float a = data[i].x * v4.x + data[i].y * v4.y
                            + data[i].z * v4.z + data[i].w * v4.w;
                    #pragma unroll
                    for (int off = 1; off <= 8; off <<= 1) a += __shfl_xor(a, off);
                    blog[i] += a;
                }
            }
        }
        // ---------------------------------------------------------------------

        if (l < 16)
            *reinterpret_cast<float4*>(out + elem * 64 + 4 * g) = v4;
    }
}

extern "C" void kernel_launch(void* const* d_in, const int* in_sizes, int n_in,
                              void* d_out, int out_size, void* d_ws, size_t ws_size,
                              hipStream_t stream) {
    const float* X = (const float*)d_in[0];
    float* out = (float*)d_out;
    const int B = in_sizes[0] / 4096;                       // 16384
    const int waves = (B + ELEMS - 1) / ELEMS;              // 2048
    const int blocks = (waves + WPB - 1) / WPB;             // 512
    routing_kernel<<<blocks, 256, 0, stream>>>(X, out, B);
}

// Round 5
// 61.049 us; speedup vs baseline: 1.0110x; 1.0110x over previous
//
#include <hip/hip_runtime.h>
#include <hip/hip_bf16.h>

// Capsule routing-by-agreement: X [B, N=64, D=64] fp32 -> v [B, 64] fp32.
// Persistent waves: one WAVE per 4-element contiguous chunk, entire 16KB tile
// register-resident, non-temporal streaming loads/stores. Zero LDS, zero
// barriers. lane l (h=l>>4, g=l&15) holds X[4i+h][4g..4g+3], i=0..15.

#define ELEMS 4   // batch elements per wave (chunked)

typedef float __attribute__((ext_vector_type(4))) f32x4;

__device__ __forceinline__ f32x4 shfl_xor4(f32x4 v, int m) {
    f32x4 r;
    r[0] = __shfl_xor(v[0], m);
    r[1] = __shfl_xor(v[1], m);
    r[2] = __shfl_xor(v[2], m);
    r[3] = __shfl_xor(v[3], m);
    return r;
}

__global__ __launch_bounds__(256)
void routing_kernel(const float* __restrict__ X, float* __restrict__ out, int B) {
    const int wid = (blockIdx.x << 2) + (threadIdx.x >> 6);
    const int l = threadIdx.x & 63;
    const int g = l & 15;

    #pragma unroll 1
    for (int e = 0; e < ELEMS; ++e) {
        const long elem = (long)wid * ELEMS + e;
        if (elem >= B) break;

        // ---- load 16KB tile, non-temporal (stream-once), coalesced 1KB/instr
        const f32x4* Xb = reinterpret_cast<const f32x4*>(X + elem * 4096) + l;
        f32x4 data[16];
        #pragma unroll
        for (int i = 0; i < 16; ++i)
            data[i] = __builtin_nontemporal_load(Xb + i * 64);

        float blog[16];
        #pragma unroll
        for (int i = 0; i < 16; ++i) blog[i] = 0.0f;
        f32x4 v4 = (f32x4)0.0f;

        #pragma unroll
        for (int it = 0; it < 3; ++it) {
            f32x4 s4 = (f32x4)0.0f;
            if (it == 0) {
                // uniform c = 1/64 -> s = mean over rows
                #pragma unroll
                for (int i = 0; i < 16; ++i) s4 += data[i];
                s4 *= 0.015625f;
            } else {
                // softmax over 64 rows fused with s-accumulate (no c[] array)
                float m = blog[0];
                #pragma unroll
                for (int i = 1; i < 16; ++i) m = fmaxf(m, blog[i]);
                m = fmaxf(m, __shfl_xor(m, 16));
                m = fmaxf(m, __shfl_xor(m, 32));
                float sum = 0.0f;
                #pragma unroll
                for (int i = 0; i < 16; ++i) {
                    const float ei = __expf(blog[i] - m);
                    sum += ei;
                    s4 += data[i] * ei;
                }
                sum += __shfl_xor(sum, 16);
                sum += __shfl_xor(sum, 32);
                const float r = 1.0f / sum;
                s4 *= r;
            }
            // reduce partial s over the 4 h-groups (rows are split across h)
            s4 += shfl_xor4(s4, 16);
            s4 += shfl_xor4(s4, 32);

            // squash: n2 = sum_d s[d]^2 via g-butterfly
            float n2 = s4[0] * s4[0] + s4[1] * s4[1] + s4[2] * s4[2] + s4[3] * s4[3];
            #pragma unroll
            for (int off = 1; off <= 8; off <<= 1) n2 += __shfl_xor(n2, off);
            const float norm = sqrtf(n2);
            const float scale = n2 / (1.0f + n2) / (norm + 1e-8f);
            v4 = s4 * scale;

            if (it < 2) {
                // agreement: b[4i+h] += X[row] . v   (v lane-local: same cols)
                #pragma unroll
                for (int i = 0; i < 16; ++i) {
                    f32x4 t = data[i] * v4;
                    float a = t[0] + t[1] + t[2] + t[3];
                    #pragma unroll
                    for (int off = 1; off <= 8; off <<= 1) a += __shfl_xor(a, off);
                    blog[i] += a;
                }
            }
        }

        // lanes h==0 (l<16) write v for cols 4g..4g+3 (256B per wave, NT)
        if (l < 16)
            __builtin_nontemporal_store(
                v4, reinterpret_cast<f32x4*>(out + elem * 64) + g);
    }
}

extern "C" void kernel_launch(void* const* d_in, const int* in_sizes, int n_in,
                              void* d_out, int out_size, void* d_ws, size_t ws_size,
                              hipStream_t stream) {
    const float* X = (const float*)d_in[0];
    float* out = (float*)d_out;
    const int B = in_sizes[0] / 4096;                 // 16384
    const int waves = (B + ELEMS - 1) / ELEMS;        // 4096 persistent waves
    const int blocks = (waves + 3) / 4;               // 1024 (4 waves/block)
    routing_kernel<<<blocks, 256, 0, stream>>>(X, out, B);
}

// Round 6
// 56.332 us; speedup vs baseline: 1.0956x; 1.0837x over previous
//
#include <hip/hip_runtime.h>
#include <hip/hip_bf16.h>

// Capsule routing-by-agreement: X [B, N=64, D=64] fp32 -> v [B, 64] fp32.
// Persistent waves (exact machine fill: 4096 waves = 256 CU x 16 waves),
// ELEMS=4 elements per wave, register-resident 16KB tile with ROTATION
// PREFETCH: next element's load for data[i] issues right after the last
// read of data[i] (final iteration's exp*fma loop) -> loads rotate into the
// same VGPRs, zero register cost, ~16KB in flight during compute tail.
// lane l (h=l>>4, g=l&15) holds X[4i+h][4g..4g+3], i=0..15. No LDS/barriers.

#define ELEMS 4

typedef float __attribute__((ext_vector_type(4))) f32x4;

__device__ __forceinline__ f32x4 shfl_xor4(f32x4 v, int m) {
    f32x4 r;
    r[0] = __shfl_xor(v[0], m);
    r[1] = __shfl_xor(v[1], m);
    r[2] = __shfl_xor(v[2], m);
    r[3] = __shfl_xor(v[3], m);
    return r;
}

__global__ __launch_bounds__(256)
void routing_kernel(const float* __restrict__ X, float* __restrict__ out, int B) {
    const int wid = (blockIdx.x << 2) + (threadIdx.x >> 6);
    const int l = threadIdx.x & 63;
    const int g = l & 15;

    const long base = (long)wid * ELEMS;
    if (base >= B) return;

    // prologue: element `base` loads
    f32x4 data[16];
    {
        const f32x4* Xb = reinterpret_cast<const f32x4*>(X + base * 4096) + l;
        #pragma unroll
        for (int i = 0; i < 16; ++i) data[i] = Xb[i * 64];
    }

    #pragma unroll 1
    for (int e = 0; e < ELEMS; ++e) {
        const long elem = base + e;
        if (elem >= B) break;
        const bool has_next = (e + 1 < ELEMS) && (elem + 1 < B);
        const f32x4* Xn = reinterpret_cast<const f32x4*>(X + (elem + 1) * 4096) + l;

        float blog[16];
        #pragma unroll
        for (int i = 0; i < 16; ++i) blog[i] = 0.0f;
        f32x4 v4 = (f32x4)0.0f;

        // ---- it 0: uniform c = 1/64 -> s = row mean ----
        f32x4 s4 = (f32x4)0.0f;
        #pragma unroll
        for (int i = 0; i < 16; ++i) s4 += data[i];   // consumes loads in order
        s4 *= 0.015625f;
        s4 += shfl_xor4(s4, 16);
        s4 += shfl_xor4(s4, 32);
        float n2 = s4[0]*s4[0] + s4[1]*s4[1] + s4[2]*s4[2] + s4[3]*s4[3];
        #pragma unroll
        for (int off = 1; off <= 8; off <<= 1) n2 += __shfl_xor(n2, off);
        float norm = sqrtf(n2);
        float scale = n2 / (1.0f + n2) / (norm + 1e-8f);
        v4 = s4 * scale;

        // agreement 0: b[4i+h] += X[row] . v
        #pragma unroll
        for (int i = 0; i < 16; ++i) {
            f32x4 t = data[i] * v4;
            float a = t[0] + t[1] + t[2] + t[3];
            #pragma unroll
            for (int off = 1; off <= 8; off <<= 1) a += __shfl_xor(a, off);
            blog[i] += a;
        }

        // ---- it 1: softmax fused with s-accumulate ----
        {
            float m = blog[0];
            #pragma unroll
            for (int i = 1; i < 16; ++i) m = fmaxf(m, blog[i]);
            m = fmaxf(m, __shfl_xor(m, 16));
            m = fmaxf(m, __shfl_xor(m, 32));
            float sum = 0.0f;
            s4 = (f32x4)0.0f;
            #pragma unroll
            for (int i = 0; i < 16; ++i) {
                const float ei = __expf(blog[i] - m);
                sum += ei;
                s4 += data[i] * ei;
            }
            sum += __shfl_xor(sum, 16);
            sum += __shfl_xor(sum, 32);
            s4 *= (1.0f / sum);
            s4 += shfl_xor4(s4, 16);
            s4 += shfl_xor4(s4, 32);
            n2 = s4[0]*s4[0] + s4[1]*s4[1] + s4[2]*s4[2] + s4[3]*s4[3];
            #pragma unroll
            for (int off = 1; off <= 8; off <<= 1) n2 += __shfl_xor(n2, off);
            norm = sqrtf(n2);
            scale = n2 / (1.0f + n2) / (norm + 1e-8f);
            v4 = s4 * scale;
        }

        // agreement 1
        #pragma unroll
        for (int i = 0; i < 16; ++i) {
            f32x4 t = data[i] * v4;
            float a = t[0] + t[1] + t[2] + t[3];
            #pragma unroll
            for (int off = 1; off <= 8; off <<= 1) a += __shfl_xor(a, off);
            blog[i] += a;
        }

        // ---- it 2: softmax + s-accumulate, WITH ROTATION PREFETCH ----
        {
            float m = blog[0];
            #pragma unroll
            for (int i = 1; i < 16; ++i) m = fmaxf(m, blog[i]);
            m = fmaxf(m, __shfl_xor(m, 16));
            m = fmaxf(m, __shfl_xor(m, 32));
            float sum = 0.0f;
            s4 = (f32x4)0.0f;
            #pragma unroll
            for (int i = 0; i < 16; ++i) {
                const float ei = __expf(blog[i] - m);
                sum += ei;
                s4 += data[i] * ei;          // LAST read of data[i]
                if (has_next)
                    data[i] = Xn[i * 64];    // prefetch next element into same reg
            }
            sum += __shfl_xor(sum, 16);
            sum += __shfl_xor(sum, 32);
            s4 *= (1.0f / sum);
            s4 += shfl_xor4(s4, 16);
            s4 += shfl_xor4(s4, 32);
            n2 = s4[0]*s4[0] + s4[1]*s4[1] + s4[2]*s4[2] + s4[3]*s4[3];
            #pragma unroll
            for (int off = 1; off <= 8; off <<= 1) n2 += __shfl_xor(n2, off);
            norm = sqrtf(n2);
            scale = n2 / (1.0f + n2) / (norm + 1e-8f);
            v4 = s4 * scale;
        }

        // store v (lanes h==0: cols 4g..4g+3; 256B per wave)
        if (l < 16)
            *(reinterpret_cast<f32x4*>(out + elem * 64) + g) = v4;
    }
}

extern "C" void kernel_launch(void* const* d_in, const int* in_sizes, int n_in,
                              void* d_out, int out_size, void* d_ws, size_t ws_size,
                              hipStream_t stream) {
    const float* X = (const float*)d_in[0];
    float* out = (float*)d_out;
    const int B = in_sizes[0] / 4096;                 // 16384
    const int waves = (B + ELEMS - 1) / ELEMS;        // 4096 = exact machine fill
    const int blocks = (waves + 3) / 4;               // 1024 (4 waves/block)
    routing_kernel<<<blocks, 256, 0, stream>>>(X, out, B);
}

// Round 7
// 48.440 us; speedup vs baseline: 1.2741x; 1.1629x over previous
//
#include <hip/hip_runtime.h>
#include <hip/hip_bf16.h>

// Capsule routing-by-agreement: X [B, N=64, D=64] fp32 -> v [B, 64] fp32.
// One WAVE per batch element (16384 waves, block-turnover pipelining),
// entire 16KB tile register-resident:
//   lane l (h=l>>4, g=l&15) holds X[4i+h][4g..4g+3], i=0..15  (16 x float4).
// All reductions are shfl_xor butterflies; zero LDS, zero barriers.
// Softmax normalization fused into the s-accumulate (no c[] array).

typedef float __attribute__((ext_vector_type(4))) f32x4;

__device__ __forceinline__ f32x4 shfl_xor4(f32x4 v, int m) {
    f32x4 r;
    r[0] = __shfl_xor(v[0], m);
    r[1] = __shfl_xor(v[1], m);
    r[2] = __shfl_xor(v[2], m);
    r[3] = __shfl_xor(v[3], m);
    return r;
}

__global__ __launch_bounds__(256)
void routing_kernel(const float* __restrict__ X, float* __restrict__ out, int B) {
    const int w = (blockIdx.x << 2) + (threadIdx.x >> 6);  // batch element
    if (w >= B) return;
    const int l = threadIdx.x & 63;
    const int g = l & 15;

    // ---- load: instr i reads a contiguous 1KB slice (coalesced) ----
    const f32x4* Xb = reinterpret_cast<const f32x4*>(X + (size_t)w * 4096) + l;
    f32x4 data[16];
    #pragma unroll
    for (int i = 0; i < 16; ++i) data[i] = Xb[i * 64];

    float blog[16];
    #pragma unroll
    for (int i = 0; i < 16; ++i) blog[i] = 0.0f;
    f32x4 v4 = (f32x4)0.0f;

    #pragma unroll
    for (int it = 0; it < 3; ++it) {
        f32x4 s4 = (f32x4)0.0f;
        if (it == 0) {
            // uniform c = 1/64 -> s = row mean
            #pragma unroll
            for (int i = 0; i < 16; ++i) s4 += data[i];
            s4 *= 0.015625f;
        } else {
            // softmax over 64 rows fused with s-accumulate
            float m = blog[0];
            #pragma unroll
            for (int i = 1; i < 16; ++i) m = fmaxf(m, blog[i]);
            m = fmaxf(m, __shfl_xor(m, 16));
            m = fmaxf(m, __shfl_xor(m, 32));
            float sum = 0.0f;
            #pragma unroll
            for (int i = 0; i < 16; ++i) {
                const float ei = __expf(blog[i] - m);
                sum += ei;
                s4 += data[i] * ei;
            }
            sum += __shfl_xor(sum, 16);
            sum += __shfl_xor(sum, 32);
            s4 *= (1.0f / sum);
        }
        // reduce partial s over the 4 h-groups
        s4 += shfl_xor4(s4, 16);
        s4 += shfl_xor4(s4, 32);

        // squash
        float n2 = s4[0]*s4[0] + s4[1]*s4[1] + s4[2]*s4[2] + s4[3]*s4[3];
        #pragma unroll
        for (int off = 1; off <= 8; off <<= 1) n2 += __shfl_xor(n2, off);
        const float norm = sqrtf(n2);
        const float scale = n2 / (1.0f + n2) / (norm + 1e-8f);
        v4 = s4 * scale;

        if (it < 2) {
            // agreement: b[4i+h] += X[row] . v   (v lane-local: same cols)
            #pragma unroll
            for (int i = 0; i < 16; ++i) {
                f32x4 t = data[i] * v4;
                float a = t[0] + t[1] + t[2] + t[3];
                #pragma unroll
                for (int off = 1; off <= 8; off <<= 1) a += __shfl_xor(a, off);
                blog[i] += a;
            }
        }
    }

    // lanes h==0 (l<16) write v for cols 4g..4g+3 (256B coalesced per wave)
    if (l < 16)
        *(reinterpret_cast<f32x4*>(out + (size_t)w * 64) + g) = v4;
}

extern "C" void kernel_launch(void* const* d_in, const int* in_sizes, int n_in,
                              void* d_out, int out_size, void* d_ws, size_t ws_size,
                              hipStream_t stream) {
    const float* X = (const float*)d_in[0];
    float* out = (float*)d_out;
    const int B = in_sizes[0] / 4096;        // 16384
    const int blocks = (B + 3) / 4;          // 4096 (4 waves/block)
    routing_kernel<<<blocks, 256, 0, stream>>>(X, out, B);
}